// Round 11
// baseline (2990.226 us; speedup 1.0000x reference)
//
#include <hip/hip_runtime.h>
#include <stdint.h>

// Problem sizes (fixed)
#define BATCH 256
#define HDIM  256
#define MDIM  128
#define NSTEPS 512

typedef unsigned short u16;
typedef unsigned int   u32;
typedef short short8 __attribute__((ext_vector_type(8)));
typedef float f32x4  __attribute__((ext_vector_type(4)));
typedef u32 u32x4 __attribute__((ext_vector_type(4)));

__device__ __forceinline__ u16 f2bf(float f) {
    u32 x = __builtin_bit_cast(u32, f);
    u32 r = x + 0x7FFFu + ((x >> 16) & 1u);
    return (u16)(r >> 16);
}
__device__ __forceinline__ float bf2f(u16 h) {
    u32 x = ((u32)h) << 16;
    return __builtin_bit_cast(float, x);
}
__device__ __forceinline__ float sigm(float x) { return 1.f / (1.f + __expf(-x)); }
__device__ __forceinline__ float tanh_f(float x) {
    float ax = fabsf(x);
    float e  = __expf(-2.f * ax);
    float t  = (1.f - e) / (1.f + e);
    return copysignf(t, x);
}
__device__ __forceinline__ f32x4 mfma16(short8 a, short8 b, f32x4 c) {
    return __builtin_amdgcn_mfma_f32_16x16x32_bf16(a, b, c, 0, 0, 0);
}

// Coherent loads. L2-tier (sc0): bypass L1, served by XCD-shared L2 — fresh
// for same-XCD producers (their sc0 sc1 stores write through L2). SYS-tier
// (sc0 sc1): LLC-coherent, guarantees progress for any placement.
#define CLOAD_L2(dst, p, OFS)                                                  \
    asm volatile("global_load_dwordx4 %0, %1, off offset:" OFS " sc0"          \
                 : "=v"(dst) : "v"(p) : "memory")
#define CLOAD_SYS(dst, p, OFS)                                                 \
    asm volatile("global_load_dwordx4 %0, %1, off offset:" OFS " sc0 sc1"      \
                 : "=v"(dst) : "v"(p) : "memory")
// Write-through store (visible at LLC; updates shared L2 en route).
#define CSTORE(p, v)                                                           \
    asm volatile("global_store_dword %0, %1, off sc0 sc1"                      \
                 :: "v"(p), "v"(v) : "memory")

#define ISSUE16(MACRO, v, base)                                                \
    MACRO(v[0],  base, "0");   MACRO(v[1],  base, "16");                       \
    MACRO(v[2],  base, "128"); MACRO(v[3],  base, "144");                      \
    MACRO(v[4],  base, "256"); MACRO(v[5],  base, "272");                      \
    MACRO(v[6],  base, "384"); MACRO(v[7],  base, "400");                      \
    MACRO(v[8],  base, "512"); MACRO(v[9],  base, "528");                      \
    MACRO(v[10], base, "640"); MACRO(v[11], base, "656");                      \
    MACRO(v[12], base, "768"); MACRO(v[13], base, "784");                      \
    MACRO(v[14], base, "896"); MACRO(v[15], base, "912")

// Spin until all 64 owned u32s carry `tag`; unpack bf16 payloads into a[].
// base = slab + (lane&15)*256 + (lane>>4)*8.  Two-tier polling (see above).
__device__ __forceinline__ void spin_load(const u32* base, u32 tag, short8 a[8]) {
    for (int it = 0;; ++it) {
        u32x4 v[16];
        const bool sys = ((it & 3) == 3);
        if (sys) { ISSUE16(CLOAD_SYS, v, base); }
        else     { ISSUE16(CLOAD_L2,  v, base); }
        asm volatile("s_waitcnt vmcnt(0)" ::: "memory");
        __builtin_amdgcn_sched_barrier(0);
        bool ok = true;
#pragma unroll
        for (int i = 0; i < 16; ++i)
#pragma unroll
            for (int j = 0; j < 4; ++j) ok = ok && ((v[i][j] >> 16) == tag);
        if (__all((int)ok)) {
#pragma unroll
            for (int kt = 0; kt < 8; ++kt)
#pragma unroll
                for (int j = 0; j < 8; ++j)
                    a[kt][j] = (short)(v[2 * kt + (j >> 2)][j & 3] & 0xFFFFu);
            return;
        }
        if (sys) __builtin_amdgcn_s_sleep(1);
    }
}

// ---------------------------------------------------------------------------
// prep: effective weights (x==h for steps>=1 collapses r,z to summed weights),
// bf16 hi/lo split, bias vector, exch zeroing (tag 0 != any step tag).
// ---------------------------------------------------------------------------
__global__ __launch_bounds__(256) void k_prep(
    const float* __restrict__ w_ih, const float* __restrict__ w_hh,
    const float* __restrict__ b_ih, const float* __restrict__ b_hh,
    const float* __restrict__ ow,   const float* __restrict__ obv,
    u16* __restrict__ Whi, u16* __restrict__ Wlo, float* __restrict__ bias,
    u32* __restrict__ exch) {
    int row = blockIdx.x;   // 0..1151
    int c   = threadIdx.x;  // 0..255
    float v;
    if (row < 512)        v = w_ih[row * HDIM + c] + w_hh[row * HDIM + c];
    else if (row < 768)   v = w_ih[row * HDIM + c];
    else if (row < 1024)  v = w_hh[(row - 256) * HDIM + c];
    else                  v = ow[(row - 1024) * HDIM + c];
    u16 hi = f2bf(v);
    u16 lo = f2bf(v - bf2f(hi));
    Whi[(size_t)row * HDIM + c] = hi;
    Wlo[(size_t)row * HDIM + c] = lo;
    if (c == 0) {
        float bv;
        if (row < 512)        bv = b_ih[row] + b_hh[row];
        else if (row < 768)   bv = b_ih[row];
        else if (row < 1024)  bv = b_hh[row - 256];
        else                  bv = obv[row - 1024];
        bias[row] = bv;
    }
    if (row < 512) exch[row * 256 + c] = 0u;  // 131072 u32 = full exch
}

// ---------------------------------------------------------------------------
// f32 tiled GEMM (prologue FNN): out[M][N] = act(A @ W^T + b)
// ---------------------------------------------------------------------------
template <int RELU>
__global__ __launch_bounds__(256) void k_gemm_f32(
    const float* __restrict__ A, const float* __restrict__ W,
    const float* __restrict__ bvec, float* __restrict__ out, int N, int K) {
    __shared__ float At[16][17];
    __shared__ float Wt[16][17];
    int tx = threadIdx.x, ty = threadIdx.y;
    int mrow = blockIdx.x * 16 + ty;
    int nrow = blockIdx.y * 16 + ty;
    float acc = 0.0f;
    for (int k0 = 0; k0 < K; k0 += 16) {
        At[ty][tx] = A[(size_t)mrow * K + k0 + tx];
        Wt[ty][tx] = W[(size_t)nrow * K + k0 + tx];
        __syncthreads();
#pragma unroll
        for (int kk = 0; kk < 16; ++kk) acc += At[ty][kk] * Wt[tx][kk];
        __syncthreads();
    }
    int n = blockIdx.y * 16 + tx;
    float r = acc + bvec[n];
    if (RELU) r = fmaxf(r, 0.0f);
    out[(size_t)mrow * N + n] = r;
}

// ---------------------------------------------------------------------------
// Persistent scan, fence-free: 256 blocks x 64 threads (1 wave each).
// Block (g,w): cluster g (16 batch rows, XCD-pinned via b&7), h-cols
// [16w,16w+16), 4 gate B-frags resident in regs (hi+lo). h exchanged as
// (tag<<16|bf16) u32 in [parity][g][row][col] slabs. Producer: 4 plain
// sc0 sc1 dword stores (write-through). Consumer: two-tier vectorized spin.
// Projection stores deferred one step so their HBM latency never sits in
// the spin's vmcnt(0) shadow; out1/out2 stores are non-temporal.
// ---------------------------------------------------------------------------
__global__ __launch_bounds__(64, 1) void k_scan(
    const u16* __restrict__ Whi, const u16* __restrict__ Wlo,
    const float* __restrict__ bias,
    const float* __restrict__ hx, const float* __restrict__ w_hh,
    const float* __restrict__ b_ih, const float* __restrict__ b_hh,
    u32* __restrict__ exch, float* __restrict__ out1, float* __restrict__ out2) {

    const int b    = blockIdx.x;
    const int w    = b >> 4;                              // 0..15 col-group
    const int g    = ((b & 7) << 1) | ((b >> 3) & 1);     // cluster, XCD-pinned
    const int lane = threadIdx.x;
    const int col_l = lane & 15;
    const int kgrp  = lane >> 4;
    const int kofs  = kgrp * 8;
    const int r0    = kgrp * 4;          // C rows r0..r0+3 (m89 layout)
    const int jcol  = w * 16 + col_l;    // owned h-column
    const int pcol  = (w & 7) * 16 + col_l;  // owned proj column
    const int myt   = w >> 3;            // project t with (t&1)==myt

    // ---- resident B fragments: gates hi+lo + proj hi ----
    short8 bhi[4][8], blo[4][8], phi[8];
#pragma unroll
    for (int g4 = 0; g4 < 4; ++g4) {
        const u16* base_hi = Whi + (size_t)(g4 * 256 + jcol) * HDIM;
        const u16* base_lo = Wlo + (size_t)(g4 * 256 + jcol) * HDIM;
#pragma unroll
        for (int kt = 0; kt < 8; ++kt) {
            bhi[g4][kt] = *(const short8*)(base_hi + kt * 32 + kofs);
            blo[g4][kt] = *(const short8*)(base_lo + kt * 32 + kofs);
        }
    }
    {
        const u16* base_p = Whi + (size_t)(1024 + pcol) * HDIM;
#pragma unroll
        for (int kt = 0; kt < 8; ++kt)
            phi[kt] = *(const short8*)(base_p + kt * 32 + kofs);
    }

    const float b_r  = bias[jcol];
    const float b_z  = bias[256 + jcol];
    const float b_in = bias[512 + jcol];
    const float b_hn = bias[768 + jcol];
    const float ob   = bias[1024 + pcol];

    // slabs: [parity][g][row][col], 4096 u32 per (parity,g)
    u32* const slab0 = exch + (size_t)(0 * 16 + g) * 4096;
    u32* const slab1 = exch + (size_t)(1 * 16 + g) * 4096;
    const int rd_off = col_l * 256 + kofs;        // consumer row-slice offset
    const int wr_off = r0 * 256 + jcol;           // producer base offset

    // ---- step 0 (one-time VALU): h_1 = cell(x=0, h=hx) -> parity 1, tag 1 ----
    float hold[4];
    {
        float ghr[4] = {0, 0, 0, 0}, ghz[4] = {0, 0, 0, 0}, ghn[4] = {0, 0, 0, 0};
        const float* wr_ = w_hh + (size_t)jcol * HDIM;
        const float* wz_ = w_hh + (size_t)(256 + jcol) * HDIM;
        const float* wn_ = w_hh + (size_t)(512 + jcol) * HDIM;
        const float* hx0 = hx + (size_t)(g * 16 + r0) * HDIM;
        for (int k = 0; k < HDIM; ++k) {
            float fr = wr_[k], fz = wz_[k], fn = wn_[k];
#pragma unroll
            for (int i = 0; i < 4; ++i) {
                float h = hx0[i * HDIM + k];
                ghr[i] += h * fr; ghz[i] += h * fz; ghn[i] += h * fn;
            }
        }
#pragma unroll
        for (int i = 0; i < 4; ++i) {
            float rr = sigm(b_ih[jcol] + b_hh[jcol] + ghr[i]);
            float zz = sigm(b_ih[256 + jcol] + b_hh[256 + jcol] + ghz[i]);
            float nn = tanh_f(b_ih[512 + jcol] + rr * (ghn[i] + b_hh[512 + jcol]));
            float hv = nn + zz * (hx0[i * HDIM + jcol] - nn);
            hold[i] = hv;
            CSTORE(slab1 + wr_off + i * 256, (1u << 16) | (u32)f2bf(hv));
        }
    }

    // ---- main loop: step s reads h_s (tag s), writes h_{s+1} ----
    f32x4 opend;            // deferred projection values (t = tpend)
    int   tpend = -1;
    for (int s = 1; s <= 511; ++s) {
        const u32* ein = ((s & 1) ? slab1 : slab0) + rd_off;
        u32*      eout = ((s & 1) ? slab0 : slab1) + wr_off;

        short8 a[8];
        spin_load(ein, (u32)s, a);

        // flush deferred projection (vmcnt just drained; full step of shadow)
        if (tpend >= 0) {
#pragma unroll
            for (int i = 0; i < 4; ++i)
                __builtin_nontemporal_store(
                    opend[i] + ob,
                    out1 + (size_t)(g * 16 + r0 + i) * (NSTEPS * MDIM) +
                        (size_t)tpend * MDIM + pcol);
        }

        f32x4 acc[4];
#pragma unroll
        for (int n = 0; n < 4; ++n) acc[n] = (f32x4){0.f, 0.f, 0.f, 0.f};
#pragma unroll
        for (int kt = 0; kt < 8; ++kt)
#pragma unroll
            for (int g4 = 0; g4 < 4; ++g4) {
                acc[g4] = mfma16(a[kt], bhi[g4][kt], acc[g4]);
                acc[g4] = mfma16(a[kt], blo[g4][kt], acc[g4]);
            }

#pragma unroll
        for (int i = 0; i < 4; ++i) {
            float rr = sigm(acc[0][i] + b_r);
            float zz = sigm(acc[1][i] + b_z);
            float nn = tanh_f(acc[2][i] + b_in + rr * (acc[3][i] + b_hn));
            float hv = nn + zz * (hold[i] - nn);
            hold[i] = hv;
            CSTORE(eout + i * 256, ((u32)(s + 1) << 16) | (u32)f2bf(hv));
        }

        // projection for t = s-1 (ys[t] = h_s = a[]); store deferred
        const int t = s - 1;
        if ((t & 1) == myt) {
            f32x4 oacc = (f32x4){0.f, 0.f, 0.f, 0.f};
#pragma unroll
            for (int kt = 0; kt < 8; ++kt) oacc = mfma16(a[kt], phi[kt], oacc);
            opend = oacc;
            tpend = t;
        }
    }

    // flush last pending projection (t=510 for myt==0, t=509 for myt==1)
    if (tpend >= 0) {
#pragma unroll
        for (int i = 0; i < 4; ++i)
            __builtin_nontemporal_store(
                opend[i] + ob,
                out1 + (size_t)(g * 16 + r0 + i) * (NSTEPS * MDIM) +
                    (size_t)tpend * MDIM + pcol);
    }

    // ---- epilogue: t=511 (odd -> myt==1) from h_512 (parity 0, tag 512) ----
    if (myt == 1) {
        short8 a[8];
        spin_load(slab0 + rd_off, 512u, a);
        f32x4 oacc = (f32x4){0.f, 0.f, 0.f, 0.f};
#pragma unroll
        for (int kt = 0; kt < 8; ++kt) oacc = mfma16(a[kt], phi[kt], oacc);
#pragma unroll
        for (int i = 0; i < 4; ++i)
            __builtin_nontemporal_store(
                oacc[i] + ob,
                out1 + (size_t)(g * 16 + r0 + i) * (NSTEPS * MDIM) +
                    511ull * MDIM + pcol);
    }

    // ---- hx_final: exact f32 h_512 ----
#pragma unroll
    for (int i = 0; i < 4; ++i)
        __builtin_nontemporal_store(
            hold[i], out2 + (size_t)(g * 16 + r0 + i) * HDIM + jcol);
}

// ---------------------------------------------------------------------------
extern "C" void kernel_launch(void* const* d_in, const int* in_sizes, int n_in,
                              void* d_out, int out_size, void* d_ws, size_t ws_size,
                              hipStream_t stream) {
    const float* P[11];
    for (int i = 0; i < 11 && i < n_in; ++i) P[i] = (const float*)d_in[i];

    // Input-order insurance (dict order confirmed by round-6 pass).
    const float *emb, *w1, *b1, *w2, *b2, *w_ih, *b_ih, *w_hh, *b_hh, *ow, *obv;
    if (n_in > 1 && in_sizes[1] == 256) {            // alphabetical
        emb = P[0]; b1 = P[1]; b2 = P[2]; w1 = P[3]; w2 = P[4];
        b_hh = P[5]; b_ih = P[6]; w_hh = P[7]; w_ih = P[8];
        obv = P[9]; ow = P[10];
    } else if (n_in > 1 && in_sizes[1] == 32768) {   // reversed dict
        obv = P[0]; ow = P[1]; b_hh = P[2]; w_hh = P[3]; b_ih = P[4];
        w_ih = P[5]; b2 = P[6]; w2 = P[7]; b1 = P[8]; w1 = P[9]; emb = P[10];
    } else {                                         // dict order (documented)
        emb = P[0]; w1 = P[1]; b1 = P[2]; w2 = P[3]; b2 = P[4];
        w_ih = P[5]; b_ih = P[6]; w_hh = P[7]; b_hh = P[8];
        ow = P[9]; obv = P[10];
    }

    float* out1 = (float*)d_out;                            // [256][512][128] f32
    float* out2 = out1 + (size_t)BATCH * NSTEPS * MDIM;     // [256][256] f32

    // ws layout (~2.13 MB)
    char* ws = (char*)d_ws;
    u16*   Whi  = (u16*)(ws + 0);            // 589824
    u16*   Wlo  = (u16*)(ws + 589824);       // 589824
    float* bias = (float*)(ws + 1179648);    // 4608
    u32*   exch = (u32*)(ws + 1184256);      // 2*16*16*256*4 = 524288
    float* mid  = (float*)(ws + 1708544);    // 262144
    float* hxb  = (float*)(ws + 1970688);    // 262144  (ends 2232832)

    k_prep<<<1152, 256, 0, stream>>>(w_ih, w_hh, b_ih, b_hh, ow, obv,
                                     Whi, Wlo, bias, exch);
    // FNN: hx = relu(emb@w1^T + b1) @ w2^T + b2
    k_gemm_f32<1><<<dim3(16, 16), dim3(16, 16), 0, stream>>>(emb, w1, b1, mid, 256, 256);
    k_gemm_f32<0><<<dim3(16, 16), dim3(16, 16), 0, stream>>>(mid, w2, b2, hxb, 256, 256);
    // Persistent scan (steps 0..511 + fused projection + finals)
    k_scan<<<256, 64, 0, stream>>>(Whi, Wlo, bias, hxb, w_hh, b_ih, b_hh,
                                   exch, out1, out2);
}

// Round 12
// 1728.245 us; speedup vs baseline: 1.7302x; 1.7302x over previous
//
#include <hip/hip_runtime.h>
#include <stdint.h>

// Problem sizes (fixed)
#define BATCH 256
#define HDIM  256
#define MDIM  128
#define NSTEPS 512

typedef unsigned short u16;
typedef unsigned int   u32;
typedef short short8 __attribute__((ext_vector_type(8)));
typedef float f32x4  __attribute__((ext_vector_type(4)));
typedef u32 u32x4 __attribute__((ext_vector_type(4)));

__device__ __forceinline__ u16 f2bf(float f) {
    u32 x = __builtin_bit_cast(u32, f);
    u32 r = x + 0x7FFFu + ((x >> 16) & 1u);
    return (u16)(r >> 16);
}
__device__ __forceinline__ float bf2f(u16 h) {
    u32 x = ((u32)h) << 16;
    return __builtin_bit_cast(float, x);
}
__device__ __forceinline__ float sigm(float x) { return 1.f / (1.f + __expf(-x)); }
__device__ __forceinline__ float tanh_f(float x) {
    float ax = fabsf(x);
    float e  = __expf(-2.f * ax);
    float t  = (1.f - e) / (1.f + e);
    return copysignf(t, x);
}
__device__ __forceinline__ f32x4 mfma16(short8 a, short8 b, f32x4 c) {
    return __builtin_amdgcn_mfma_f32_16x16x32_bf16(a, b, c, 0, 0, 0);
}

// L2-tier load (sc0): bypass L1, served by the XCD-shared L2 — sees plain
// stores from same-XCD producers (L1 is write-through, L2 write-back).
#define CLOAD_L2(dst, p, OFS)                                                  \
    asm volatile("global_load_dwordx4 %0, %1, off offset:" OFS " sc0"          \
                 : "=v"(dst) : "v"(p) : "memory")
// SYS-tier load (sc0 sc1): LLC-coherent, guarantees progress for any placement.
#define CLOAD_SYS(dst, p, OFS)                                                 \
    asm volatile("global_load_dwordx4 %0, %1, off offset:" OFS " sc0 sc1"      \
                 : "=v"(dst) : "v"(p) : "memory")
// Plain store: lands (and stays) dirty in the producer XCD's L2.
#define CSTORE_LOC(p, v)                                                       \
    asm volatile("global_store_dword %0, %1, off"                              \
                 :: "v"(p), "v"(v) : "memory")
// Write-through store: visible at LLC for cross-XCD consumers.
#define CSTORE_SYS(p, v)                                                       \
    asm volatile("global_store_dword %0, %1, off sc0 sc1"                      \
                 :: "v"(p), "v"(v) : "memory")

#define ISSUE16(MACRO, v, base)                                                \
    MACRO(v[0],  base, "0");   MACRO(v[1],  base, "16");                       \
    MACRO(v[2],  base, "128"); MACRO(v[3],  base, "144");                      \
    MACRO(v[4],  base, "256"); MACRO(v[5],  base, "272");                      \
    MACRO(v[6],  base, "384"); MACRO(v[7],  base, "400");                      \
    MACRO(v[8],  base, "512"); MACRO(v[9],  base, "528");                      \
    MACRO(v[10], base, "640"); MACRO(v[11], base, "656");                      \
    MACRO(v[12], base, "768"); MACRO(v[13], base, "784");                      \
    MACRO(v[14], base, "896"); MACRO(v[15], base, "912")

// Spin until all 64 owned u32s carry exactly `tag`; unpack bf16 payloads.
// Alternates: even polls = fast local-L2 read of slabL; odd polls = coherent
// LLC read of slabM. Tag-in-data makes stale reads harmless; slabM polling
// guarantees liveness regardless of XCD placement.
__device__ __forceinline__ void spin_load(const u32* baseL, const u32* baseM,
                                          u32 tag, short8 a[8]) {
    for (int it = 0;; ++it) {
        u32x4 v[16];
        const bool sys = (it & 1);
        if (sys) { ISSUE16(CLOAD_SYS, v, baseM); }
        else     { ISSUE16(CLOAD_L2,  v, baseL); }
        asm volatile("s_waitcnt vmcnt(0)" ::: "memory");
        __builtin_amdgcn_sched_barrier(0);
        bool ok = true;
#pragma unroll
        for (int i = 0; i < 16; ++i)
#pragma unroll
            for (int j = 0; j < 4; ++j) ok = ok && ((v[i][j] >> 16) == tag);
        if (__all((int)ok)) {
#pragma unroll
            for (int kt = 0; kt < 8; ++kt)
#pragma unroll
                for (int j = 0; j < 8; ++j)
                    a[kt][j] = (short)(v[2 * kt + (j >> 2)][j & 3] & 0xFFFFu);
            return;
        }
        if (sys) __builtin_amdgcn_s_sleep(1);
    }
}

// ---------------------------------------------------------------------------
// prep: effective weights (x==h for steps>=1 collapses r,z to summed weights),
// bf16 hi/lo split, bias vector, exch zeroing (tag 0 != any step tag).
// ---------------------------------------------------------------------------
__global__ __launch_bounds__(256) void k_prep(
    const float* __restrict__ w_ih, const float* __restrict__ w_hh,
    const float* __restrict__ b_ih, const float* __restrict__ b_hh,
    const float* __restrict__ ow,   const float* __restrict__ obv,
    u16* __restrict__ Whi, u16* __restrict__ Wlo, float* __restrict__ bias,
    u32* __restrict__ exch) {
    int row = blockIdx.x;   // 0..1151
    int c   = threadIdx.x;  // 0..255
    float v;
    if (row < 512)        v = w_ih[row * HDIM + c] + w_hh[row * HDIM + c];
    else if (row < 768)   v = w_ih[row * HDIM + c];
    else if (row < 1024)  v = w_hh[(row - 256) * HDIM + c];
    else                  v = ow[(row - 1024) * HDIM + c];
    u16 hi = f2bf(v);
    u16 lo = f2bf(v - bf2f(hi));
    Whi[(size_t)row * HDIM + c] = hi;
    Wlo[(size_t)row * HDIM + c] = lo;
    if (c == 0) {
        float bv;
        if (row < 512)        bv = b_ih[row] + b_hh[row];
        else if (row < 768)   bv = b_ih[row];
        else if (row < 1024)  bv = b_hh[row - 256];
        else                  bv = obv[row - 1024];
        bias[row] = bv;
    }
    if (row < 1024) exch[row * 256 + c] = 0u;  // 262144 u32 = slabL + slabM
}

// ---------------------------------------------------------------------------
// f32 tiled GEMM (prologue FNN): out[M][N] = act(A @ W^T + b)
// ---------------------------------------------------------------------------
template <int RELU>
__global__ __launch_bounds__(256) void k_gemm_f32(
    const float* __restrict__ A, const float* __restrict__ W,
    const float* __restrict__ bvec, float* __restrict__ out, int N, int K) {
    __shared__ float At[16][17];
    __shared__ float Wt[16][17];
    int tx = threadIdx.x, ty = threadIdx.y;
    int mrow = blockIdx.x * 16 + ty;
    int nrow = blockIdx.y * 16 + ty;
    float acc = 0.0f;
    for (int k0 = 0; k0 < K; k0 += 16) {
        At[ty][tx] = A[(size_t)mrow * K + k0 + tx];
        Wt[ty][tx] = W[(size_t)nrow * K + k0 + tx];
        __syncthreads();
#pragma unroll
        for (int kk = 0; kk < 16; ++kk) acc += At[ty][kk] * Wt[tx][kk];
        __syncthreads();
    }
    int n = blockIdx.y * 16 + tx;
    float r = acc + bvec[n];
    if (RELU) r = fmaxf(r, 0.0f);
    out[(size_t)mrow * N + n] = r;
}

// ---------------------------------------------------------------------------
// Persistent scan, dual-slab fence-free: 256 blocks x 64 threads (1 wave).
// Block (g,w): cluster g (16 batch rows; all 16 blocks of g share b&7 ->
// same XCD under round-robin), h-cols [16w,16w+16), gate B-frags resident.
// h exchanged as (tag<<16|bf16): plain store -> slabL (XCD L2, fast path)
// AND sc0 sc1 store -> slabM (LLC, liveness). Consumer alternates L2/SYS
// polls. Projection stores deferred one step (flushed after spin success).
// ---------------------------------------------------------------------------
__global__ __launch_bounds__(64, 1) void k_scan(
    const u16* __restrict__ Whi, const u16* __restrict__ Wlo,
    const float* __restrict__ bias,
    const float* __restrict__ hx, const float* __restrict__ w_hh,
    const float* __restrict__ b_ih, const float* __restrict__ b_hh,
    u32* __restrict__ exch, float* __restrict__ out1, float* __restrict__ out2) {

    const int b    = blockIdx.x;
    const int w    = b >> 4;                              // 0..15 col-group
    const int g    = ((b & 7) << 1) | ((b >> 3) & 1);     // cluster, XCD-pinned
    const int lane = threadIdx.x;
    const int col_l = lane & 15;
    const int kgrp  = lane >> 4;
    const int kofs  = kgrp * 8;
    const int r0    = kgrp * 4;          // C rows r0..r0+3 (m89 layout)
    const int jcol  = w * 16 + col_l;    // owned h-column
    const int pcol  = (w & 7) * 16 + col_l;  // owned proj column
    const int myt   = w >> 3;            // project t with (t&1)==myt

    // ---- resident B fragments: gates hi+lo + proj hi ----
    short8 bhi[4][8], blo[4][8], phi[8];
#pragma unroll
    for (int g4 = 0; g4 < 4; ++g4) {
        const u16* base_hi = Whi + (size_t)(g4 * 256 + jcol) * HDIM;
        const u16* base_lo = Wlo + (size_t)(g4 * 256 + jcol) * HDIM;
#pragma unroll
        for (int kt = 0; kt < 8; ++kt) {
            bhi[g4][kt] = *(const short8*)(base_hi + kt * 32 + kofs);
            blo[g4][kt] = *(const short8*)(base_lo + kt * 32 + kofs);
        }
    }
    {
        const u16* base_p = Whi + (size_t)(1024 + pcol) * HDIM;
#pragma unroll
        for (int kt = 0; kt < 8; ++kt)
            phi[kt] = *(const short8*)(base_p + kt * 32 + kofs);
    }

    const float b_r  = bias[jcol];
    const float b_z  = bias[256 + jcol];
    const float b_in = bias[512 + jcol];
    const float b_hn = bias[768 + jcol];
    const float ob   = bias[1024 + pcol];

    // slabs: [tier][parity][g][row][col]; 4096 u32 per (parity,g)
    u32* const L0 = exch + (size_t)(0 * 16 + g) * 4096;
    u32* const L1 = exch + (size_t)(1 * 16 + g) * 4096;
    u32* const M0 = exch + 131072 + (size_t)(0 * 16 + g) * 4096;
    u32* const M1 = exch + 131072 + (size_t)(1 * 16 + g) * 4096;
    const int rd_off = col_l * 256 + kofs;        // consumer row-slice offset
    const int wr_off = r0 * 256 + jcol;           // producer base offset

    // ---- step 0 (one-time VALU): h_1 = cell(x=0, h=hx) -> parity 1, tag 1 ----
    float hold[4];
    {
        float ghr[4] = {0, 0, 0, 0}, ghz[4] = {0, 0, 0, 0}, ghn[4] = {0, 0, 0, 0};
        const float* wr_ = w_hh + (size_t)jcol * HDIM;
        const float* wz_ = w_hh + (size_t)(256 + jcol) * HDIM;
        const float* wn_ = w_hh + (size_t)(512 + jcol) * HDIM;
        const float* hx0 = hx + (size_t)(g * 16 + r0) * HDIM;
        for (int k = 0; k < HDIM; ++k) {
            float fr = wr_[k], fz = wz_[k], fn = wn_[k];
#pragma unroll
            for (int i = 0; i < 4; ++i) {
                float h = hx0[i * HDIM + k];
                ghr[i] += h * fr; ghz[i] += h * fz; ghn[i] += h * fn;
            }
        }
#pragma unroll
        for (int i = 0; i < 4; ++i) {
            float rr = sigm(b_ih[jcol] + b_hh[jcol] + ghr[i]);
            float zz = sigm(b_ih[256 + jcol] + b_hh[256 + jcol] + ghz[i]);
            float nn = tanh_f(b_ih[512 + jcol] + rr * (ghn[i] + b_hh[512 + jcol]));
            float hv = nn + zz * (hx0[i * HDIM + jcol] - nn);
            hold[i] = hv;
            u32 pk = (1u << 16) | (u32)f2bf(hv);
            CSTORE_LOC(L1 + wr_off + i * 256, pk);
            CSTORE_SYS(M1 + wr_off + i * 256, pk);
        }
    }

    // ---- main loop: step s reads h_s (tag s), writes h_{s+1} ----
    f32x4 opend;            // deferred projection values (t = tpend)
    int   tpend = -1;
    for (int s = 1; s <= 511; ++s) {
        const u32* einL = ((s & 1) ? L1 : L0) + rd_off;
        const u32* einM = ((s & 1) ? M1 : M0) + rd_off;
        u32*      eoutL = ((s & 1) ? L0 : L1) + wr_off;
        u32*      eoutM = ((s & 1) ? M0 : M1) + wr_off;

        short8 a[8];
        spin_load(einL, einM, (u32)s, a);

        // flush deferred projection (vmcnt just drained; full step of shadow)
        if (tpend >= 0) {
#pragma unroll
            for (int i = 0; i < 4; ++i)
                __builtin_nontemporal_store(
                    opend[i] + ob,
                    out1 + (size_t)(g * 16 + r0 + i) * (NSTEPS * MDIM) +
                        (size_t)tpend * MDIM + pcol);
        }

        f32x4 acc[4];
#pragma unroll
        for (int n = 0; n < 4; ++n) acc[n] = (f32x4){0.f, 0.f, 0.f, 0.f};
#pragma unroll
        for (int kt = 0; kt < 8; ++kt)
#pragma unroll
            for (int g4 = 0; g4 < 4; ++g4) {
                acc[g4] = mfma16(a[kt], bhi[g4][kt], acc[g4]);
                acc[g4] = mfma16(a[kt], blo[g4][kt], acc[g4]);
            }

        u32 pk[4];
#pragma unroll
        for (int i = 0; i < 4; ++i) {
            float rr = sigm(acc[0][i] + b_r);
            float zz = sigm(acc[1][i] + b_z);
            float nn = tanh_f(acc[2][i] + b_in + rr * (acc[3][i] + b_hn));
            float hv = nn + zz * (hold[i] - nn);
            hold[i] = hv;
            pk[i] = ((u32)(s + 1) << 16) | (u32)f2bf(hv);
        }
        // local stores first (unblock same-XCD consumers earliest), then LLC
#pragma unroll
        for (int i = 0; i < 4; ++i) CSTORE_LOC(eoutL + i * 256, pk[i]);
#pragma unroll
        for (int i = 0; i < 4; ++i) CSTORE_SYS(eoutM + i * 256, pk[i]);

        // projection for t = s-1 (ys[t] = h_s = a[]); store deferred
        const int t = s - 1;
        if ((t & 1) == myt) {
            f32x4 oacc = (f32x4){0.f, 0.f, 0.f, 0.f};
#pragma unroll
            for (int kt = 0; kt < 8; ++kt) oacc = mfma16(a[kt], phi[kt], oacc);
            opend = oacc;
            tpend = t;
        }
    }

    // flush last pending projection
    if (tpend >= 0) {
#pragma unroll
        for (int i = 0; i < 4; ++i)
            __builtin_nontemporal_store(
                opend[i] + ob,
                out1 + (size_t)(g * 16 + r0 + i) * (NSTEPS * MDIM) +
                    (size_t)tpend * MDIM + pcol);
    }

    // ---- epilogue: t=511 (odd -> myt==1) from h_512 (parity 0, tag 512) ----
    if (myt == 1) {
        short8 a[8];
        spin_load(L0 + rd_off, M0 + rd_off, 512u, a);
        f32x4 oacc = (f32x4){0.f, 0.f, 0.f, 0.f};
#pragma unroll
        for (int kt = 0; kt < 8; ++kt) oacc = mfma16(a[kt], phi[kt], oacc);
#pragma unroll
        for (int i = 0; i < 4; ++i)
            __builtin_nontemporal_store(
                oacc[i] + ob,
                out1 + (size_t)(g * 16 + r0 + i) * (NSTEPS * MDIM) +
                    511ull * MDIM + pcol);
    }

    // ---- hx_final: exact f32 h_512 ----
#pragma unroll
    for (int i = 0; i < 4; ++i)
        __builtin_nontemporal_store(
            hold[i], out2 + (size_t)(g * 16 + r0 + i) * HDIM + jcol);
}

// ---------------------------------------------------------------------------
extern "C" void kernel_launch(void* const* d_in, const int* in_sizes, int n_in,
                              void* d_out, int out_size, void* d_ws, size_t ws_size,
                              hipStream_t stream) {
    const float* P[11];
    for (int i = 0; i < 11 && i < n_in; ++i) P[i] = (const float*)d_in[i];

    // Input-order insurance (dict order confirmed by round-6 pass).
    const float *emb, *w1, *b1, *w2, *b2, *w_ih, *b_ih, *w_hh, *b_hh, *ow, *obv;
    if (n_in > 1 && in_sizes[1] == 256) {            // alphabetical
        emb = P[0]; b1 = P[1]; b2 = P[2]; w1 = P[3]; w2 = P[4];
        b_hh = P[5]; b_ih = P[6]; w_hh = P[7]; w_ih = P[8];
        obv = P[9]; ow = P[10];
    } else if (n_in > 1 && in_sizes[1] == 32768) {   // reversed dict
        obv = P[0]; ow = P[1]; b_hh = P[2]; w_hh = P[3]; b_ih = P[4];
        w_ih = P[5]; b2 = P[6]; w2 = P[7]; b1 = P[8]; w1 = P[9]; emb = P[10];
    } else {                                         // dict order (documented)
        emb = P[0]; w1 = P[1]; b1 = P[2]; w2 = P[3]; b2 = P[4];
        w_ih = P[5]; b_ih = P[6]; w_hh = P[7]; b_hh = P[8];
        ow = P[9]; obv = P[10];
    }

    float* out1 = (float*)d_out;                            // [256][512][128] f32
    float* out2 = out1 + (size_t)BATCH * NSTEPS * MDIM;     // [256][256] f32

    // ws layout (~2.76 MB)
    char* ws = (char*)d_ws;
    u16*   Whi  = (u16*)(ws + 0);            // 589824
    u16*   Wlo  = (u16*)(ws + 589824);       // 589824
    float* bias = (float*)(ws + 1179648);    // 4608
    u32*   exch = (u32*)(ws + 1184256);      // 2 tiers * 524288 = 1048576
    float* mid  = (float*)(ws + 2232832);    // 262144
    float* hxb  = (float*)(ws + 2494976);    // 262144  (ends 2757120)

    k_prep<<<1152, 256, 0, stream>>>(w_ih, w_hh, b_ih, b_hh, ow, obv,
                                     Whi, Wlo, bias, exch);
    // FNN: hx = relu(emb@w1^T + b1) @ w2^T + b2
    k_gemm_f32<1><<<dim3(16, 16), dim3(16, 16), 0, stream>>>(emb, w1, b1, mid, 256, 256);
    k_gemm_f32<0><<<dim3(16, 16), dim3(16, 16), 0, stream>>>(mid, w2, b2, hxb, 256, 256);
    // Persistent scan (steps 0..511 + fused projection + finals)
    k_scan<<<256, 64, 0, stream>>>(Whi, Wlo, bias, hxb, w_hh, b_ih, b_hh,
                                   exch, out1, out2);
}